// Round 10
// baseline (1759.714 us; speedup 1.0000x reference)
//
#include <hip/hip_runtime.h>

// ---------------------------------------------------------------------------
// GCN, 6 layers, N=1M nodes, E=16M edges.
// R10: latency attack. R4-R9 invariant (~262us / 3-feat layer) is modeled as
// per-CU outstanding-miss cap (~64-80) x ~650cyc L3-ish latency. Fix: sort
// each dst-bucket's edges FULLY BY SRC (64-node granularity, 16K bins, int
// counters in 68KB LDS -- no u16 overflow skip like R9). All 245 blocks then
// sweep src 0->1M in identical order/rate (1 block/CU, equal edge counts):
// a self-synchronizing sliding window of ~2MB that stays resident in each
// XCD's 4MB L2 -> gathers become ~200cyc L2 hits -> ~3x edge throughput at
// fixed miss concurrency. Build: 256 dst-bins only (pscatter runs ~244 edges,
// low write-amp); the per-bucket src sort supersedes finer ordering.
// Layer 6 applies W6 before aggregation (right-mult commutes with A).
// ---------------------------------------------------------------------------

#define BT 256            // build-kernel block size
#define NBLK 256          // partition blocks
#define BSHIFT 12         // 4096 nodes per dst bucket
#define BSIZE 4096
#define LMASK 4095
#define NBKT 256          // dst bins (>= ceil(1e6/4096)=245)
#define M (NBLK * NBKT)   // 65536
#define BTL 1024          // layer/sort kernel block size
#define NSB 16384         // src-sort bins: src>>6 (20-6=14 bits)
#define CAP 72            // staged edges/thread in k_sortB (covers 73728/bucket)

// s0 = feat * norm
__global__ void k_init(const float* __restrict__ feat, const float* __restrict__ norm,
                       float* __restrict__ s0, int N) {
  int i = blockIdx.x * BT + threadIdx.x;
  if (i < N) s0[i] = feat[i] * norm[i];
}

// P1: per-block LDS histogram of dst buckets (256 bins)
__global__ void k_phist(const int* __restrict__ dst, int* __restrict__ histB,
                        int E, int chunk) {
  __shared__ int h[NBKT];
  if (threadIdx.x < NBKT) h[threadIdx.x] = 0;
  __syncthreads();
  int b = blockIdx.x;
  int beg = b * chunk, end = min(beg + chunk, E);
  int i = beg + (int)threadIdx.x * 4;  // beg 16B-aligned (chunk % 4 == 0)
  for (; i + 3 < end; i += BT * 4) {
    int4 v = *(const int4*)(dst + i);
    atomicAdd(&h[v.x >> BSHIFT], 1);
    atomicAdd(&h[v.y >> BSHIFT], 1);
    atomicAdd(&h[v.z >> BSHIFT], 1);
    atomicAdd(&h[v.w >> BSHIFT], 1);
  }
  for (; i < end; ++i) atomicAdd(&h[dst[i] >> BSHIFT], 1);
  __syncthreads();
  if (threadIdx.x < NBKT) histB[b * NBKT + threadIdx.x] = h[threadIdx.x];
}

// Tiled transpose: in[R][C] -> out[C][R]. R,C multiples of 64. grid(C/64,R/64)
__global__ void k_transp(const int* __restrict__ in, int* __restrict__ out, int R, int C) {
  __shared__ int tile[64][65];
  int c0 = blockIdx.x * 64, r0 = blockIdx.y * 64;
  int tx = threadIdx.x & 63, ty = threadIdx.x >> 6;
  for (int j = 0; j < 16; ++j) {
    int r = ty + j * 4;
    tile[r][tx] = in[(r0 + r) * C + c0 + tx];
  }
  __syncthreads();
  for (int j = 0; j < 16; ++j) {
    int r = ty + j * 4;
    out[(c0 + r) * R + r0 + tx] = tile[tx][r];
  }
}

// scan A: per-block sums
__global__ void k_blockSum(const int* __restrict__ data, int* __restrict__ partial, int Mlen) {
  __shared__ int tmp[BT];
  int i = blockIdx.x * BT + threadIdx.x;
  tmp[threadIdx.x] = (i < Mlen) ? data[i] : 0;
  __syncthreads();
  for (int off = BT / 2; off > 0; off >>= 1) {
    if (threadIdx.x < off) tmp[threadIdx.x] += tmp[threadIdx.x + off];
    __syncthreads();
  }
  if (threadIdx.x == 0) partial[blockIdx.x] = tmp[0];
}

// scan B: exclusive scan of partials in place (single block)
__global__ void k_scanPartials(int* __restrict__ partial, int nb) {
  __shared__ int tmp[BT];
  __shared__ int carry;
  int t = threadIdx.x;
  if (t == 0) carry = 0;
  __syncthreads();
  for (int base = 0; base < nb; base += BT) {
    int i = base + t;
    int v = (i < nb) ? partial[i] : 0;
    tmp[t] = v;
    __syncthreads();
    for (int off = 1; off < BT; off <<= 1) {
      int x = 0;
      if (t >= off) x = tmp[t - off];
      __syncthreads();
      tmp[t] += x;
      __syncthreads();
    }
    if (i < nb) partial[i] = tmp[t] - v + carry;
    __syncthreads();
    if (t == BT - 1) carry += tmp[BT - 1];
    __syncthreads();
  }
}

// scan C: final exclusive scan in place
__global__ void k_scanFinal(int* __restrict__ data, const int* __restrict__ partial, int Mlen) {
  __shared__ int tmp[BT];
  int t = threadIdx.x;
  int i = blockIdx.x * BT + t;
  int v = (i < Mlen) ? data[i] : 0;
  tmp[t] = v;
  __syncthreads();
  for (int off = 1; off < BT; off <<= 1) {
    int x = 0;
    if (t >= off) x = tmp[t - off];
    __syncthreads();
    tmp[t] += x;
    __syncthreads();
  }
  if (i < Mlen) data[i] = tmp[t] - v + partial[blockIdx.x];
}

// P2: scatter packed edges with per-block LDS cursors (256 bins)
__global__ void k_pscatter(const int* __restrict__ src, const int* __restrict__ dst,
                           const int* __restrict__ scanT, unsigned int* __restrict__ packed,
                           int E, int chunk) {
  __shared__ int cur[NBKT];
  int b = blockIdx.x;
  if (threadIdx.x < NBKT) cur[threadIdx.x] = scanT[b * NBKT + threadIdx.x];
  __syncthreads();
  int beg = b * chunk, end = min(beg + chunk, E);
  int i = beg + (int)threadIdx.x * 4;
  for (; i + 3 < end; i += BT * 4) {
    int4 u = *(const int4*)(src + i);
    int4 v = *(const int4*)(dst + i);
    int p;
    p = atomicAdd(&cur[v.x >> BSHIFT], 1);
    packed[p] = ((unsigned)u.x << BSHIFT) | (unsigned)(v.x & LMASK);
    p = atomicAdd(&cur[v.y >> BSHIFT], 1);
    packed[p] = ((unsigned)u.y << BSHIFT) | (unsigned)(v.y & LMASK);
    p = atomicAdd(&cur[v.z >> BSHIFT], 1);
    packed[p] = ((unsigned)u.z << BSHIFT) | (unsigned)(v.z & LMASK);
    p = atomicAdd(&cur[v.w >> BSHIFT], 1);
    packed[p] = ((unsigned)u.w << BSHIFT) | (unsigned)(v.w & LMASK);
  }
  for (; i < end; ++i) {
    int p = atomicAdd(&cur[dst[i] >> BSHIFT], 1);
    packed[p] = ((unsigned)src[i] << BSHIFT) | (unsigned)(dst[i] & LMASK);
  }
}

// P3: in-place counting sort of each bucket's edges by src>>6 (16K bins,
// full-int counters: 64KB cnt + 4KB tsum LDS). Edges staged in registers.
__global__ __launch_bounds__(BTL) void k_sortB(const int* __restrict__ scanT,
                                               unsigned int* __restrict__ packed) {
  __shared__ int cnt[NSB];
  __shared__ int tsum[BTL];
  int k = blockIdx.x;
  int beg = scanT[k], end = scanT[k + 1];
  if (end - beg > CAP * BTL) return;  // impossible statistically; correctness-safe
  int t = threadIdx.x;
  for (int i = t; i < NSB; i += BTL) cnt[i] = 0;
  __syncthreads();
  unsigned e[CAP];
#pragma unroll
  for (int j = 0; j < CAP; ++j) {
    int i = beg + t + j * BTL;
    if (i < end) {
      unsigned p = packed[i];
      e[j] = p;
      atomicAdd(&cnt[p >> 18], 1);  // src>>6 == (p>>12)>>6
    }
  }
  __syncthreads();
  int base16 = t * 16;
  int s = 0;
#pragma unroll
  for (int j = 0; j < 16; ++j) s += cnt[base16 + j];
  tsum[t] = s;
  __syncthreads();
  for (int off = 1; off < BTL; off <<= 1) {
    int x = 0;
    if (t >= off) x = tsum[t - off];
    __syncthreads();
    tsum[t] += x;
    __syncthreads();
  }
  int run = tsum[t] - s;
#pragma unroll
  for (int j = 0; j < 16; ++j) {
    int c = cnt[base16 + j];
    cnt[base16 + j] = run;
    run += c;
  }
  __syncthreads();
#pragma unroll
  for (int j = 0; j < CAP; ++j) {
    int i = beg + t + j * BTL;
    if (i < end) {
      unsigned p = e[j];
      int pos = atomicAdd(&cnt[p >> 18], 1);
      packed[beg + pos] = p;
    }
  }
}

// --- layer kernels: one block per dst bucket, [scanT[k], scanT[k+1]) ---
// Edge stream is src-ascending: all blocks sweep the same sliding src window.

#define ACC3(p)                                             \
  {                                                         \
    unsigned pp = (p);                                      \
    float4 m = ((const float4*)sPrev)[pp >> BSHIFT];        \
    int loc = pp & LMASK;                                   \
    atomicAdd(&a0[loc], m.x);                               \
    atomicAdd(&a1[loc], m.y);                               \
    atomicAdd(&a2[loc], m.z);                               \
  }

#define ACC1(p)                                             \
  {                                                         \
    unsigned pp = (p);                                      \
    atomicAdd(&a[pp & LMASK], sIn[pp >> BSHIFT]);           \
  }

// Layer 1 (1->3)
__global__ __launch_bounds__(BTL) void k_layer1(
    const int* __restrict__ scanT, const unsigned int* __restrict__ packed,
    const float* __restrict__ sIn, const float* __restrict__ norm,
    const float* __restrict__ W1, const float* __restrict__ b1,
    float* __restrict__ sNext, int N) {
  __shared__ float a[BSIZE];
  int k = blockIdx.x;
  for (int i = threadIdx.x; i < BSIZE; i += BTL) a[i] = 0.0f;
  int beg = scanT[k], end = scanT[k + 1];
  __syncthreads();
  int abeg = min(end, (beg + 7) & ~7);
  {
    int t = beg + (int)threadIdx.x;
    if (t < abeg) ACC1(packed[t]);
  }
  int i = abeg + (int)threadIdx.x * 8;
  for (; i + 7 < end; i += BTL * 8) {
    uint4 pa = *(const uint4*)(packed + i);
    uint4 pb = *(const uint4*)(packed + i + 4);
    float m0 = sIn[pa.x >> BSHIFT];
    float m1 = sIn[pa.y >> BSHIFT];
    float m2 = sIn[pa.z >> BSHIFT];
    float m3 = sIn[pa.w >> BSHIFT];
    float m4 = sIn[pb.x >> BSHIFT];
    float m5 = sIn[pb.y >> BSHIFT];
    float m6 = sIn[pb.z >> BSHIFT];
    float m7 = sIn[pb.w >> BSHIFT];
    atomicAdd(&a[pa.x & LMASK], m0);
    atomicAdd(&a[pa.y & LMASK], m1);
    atomicAdd(&a[pa.z & LMASK], m2);
    atomicAdd(&a[pa.w & LMASK], m3);
    atomicAdd(&a[pb.x & LMASK], m4);
    atomicAdd(&a[pb.y & LMASK], m5);
    atomicAdd(&a[pb.z & LMASK], m6);
    atomicAdd(&a[pb.w & LMASK], m7);
  }
  for (; i < end; ++i) ACC1(packed[i]);
  __syncthreads();
  int node0 = k << BSHIFT;
  for (int tt = threadIdx.x; tt < BSIZE; tt += BTL) {
    int node = node0 + tt;
    if (node >= N) break;
    float n = norm[node];
    float pre = a[tt] * n;
    float h0 = fmaxf(0.0f, pre * W1[0] + b1[0]);
    float h1 = fmaxf(0.0f, pre * W1[1] + b1[1]);
    float h2 = fmaxf(0.0f, pre * W1[2] + b1[2]);
    ((float4*)sNext)[node] = make_float4(h0 * n, h1 * n, h2 * n, 0.0f);
  }
}

// Layers 2-4 (3->3)
__global__ __launch_bounds__(BTL) void k_layer3(
    const int* __restrict__ scanT, const unsigned int* __restrict__ packed,
    const float* __restrict__ sPrev, const float* __restrict__ norm,
    const float* __restrict__ W, const float* __restrict__ bias,
    float* __restrict__ sNext, int N) {
  __shared__ float a0[BSIZE], a1[BSIZE], a2[BSIZE];
  int k = blockIdx.x;
  for (int i = threadIdx.x; i < BSIZE; i += BTL) { a0[i] = 0.0f; a1[i] = 0.0f; a2[i] = 0.0f; }
  int beg = scanT[k], end = scanT[k + 1];
  __syncthreads();
  int abeg = min(end, (beg + 7) & ~7);
  {
    int t = beg + (int)threadIdx.x;
    if (t < abeg) ACC3(packed[t]);
  }
  int i = abeg + (int)threadIdx.x * 8;
  for (; i + 7 < end; i += BTL * 8) {
    uint4 pa = *(const uint4*)(packed + i);
    uint4 pb = *(const uint4*)(packed + i + 4);
    float4 m0 = ((const float4*)sPrev)[pa.x >> BSHIFT];
    float4 m1 = ((const float4*)sPrev)[pa.y >> BSHIFT];
    float4 m2 = ((const float4*)sPrev)[pa.z >> BSHIFT];
    float4 m3 = ((const float4*)sPrev)[pa.w >> BSHIFT];
    float4 m4 = ((const float4*)sPrev)[pb.x >> BSHIFT];
    float4 m5 = ((const float4*)sPrev)[pb.y >> BSHIFT];
    float4 m6 = ((const float4*)sPrev)[pb.z >> BSHIFT];
    float4 m7 = ((const float4*)sPrev)[pb.w >> BSHIFT];
    atomicAdd(&a0[pa.x & LMASK], m0.x); atomicAdd(&a1[pa.x & LMASK], m0.y); atomicAdd(&a2[pa.x & LMASK], m0.z);
    atomicAdd(&a0[pa.y & LMASK], m1.x); atomicAdd(&a1[pa.y & LMASK], m1.y); atomicAdd(&a2[pa.y & LMASK], m1.z);
    atomicAdd(&a0[pa.z & LMASK], m2.x); atomicAdd(&a1[pa.z & LMASK], m2.y); atomicAdd(&a2[pa.z & LMASK], m2.z);
    atomicAdd(&a0[pa.w & LMASK], m3.x); atomicAdd(&a1[pa.w & LMASK], m3.y); atomicAdd(&a2[pa.w & LMASK], m3.z);
    atomicAdd(&a0[pb.x & LMASK], m4.x); atomicAdd(&a1[pb.x & LMASK], m4.y); atomicAdd(&a2[pb.x & LMASK], m4.z);
    atomicAdd(&a0[pb.y & LMASK], m5.x); atomicAdd(&a1[pb.y & LMASK], m5.y); atomicAdd(&a2[pb.y & LMASK], m5.z);
    atomicAdd(&a0[pb.z & LMASK], m6.x); atomicAdd(&a1[pb.z & LMASK], m6.y); atomicAdd(&a2[pb.z & LMASK], m6.z);
    atomicAdd(&a0[pb.w & LMASK], m7.x); atomicAdd(&a1[pb.w & LMASK], m7.y); atomicAdd(&a2[pb.w & LMASK], m7.z);
  }
  for (; i < end; ++i) ACC3(packed[i]);
  __syncthreads();
  int node0 = k << BSHIFT;
  for (int tt = threadIdx.x; tt < BSIZE; tt += BTL) {
    int node = node0 + tt;
    if (node >= N) break;
    float n = norm[node];
    float x0 = a0[tt] * n, x1 = a1[tt] * n, x2 = a2[tt] * n;
    float h0 = fmaxf(0.0f, x0 * W[0] + x1 * W[3] + x2 * W[6] + bias[0]);
    float h1 = fmaxf(0.0f, x0 * W[1] + x1 * W[4] + x2 * W[7] + bias[1]);
    float h2 = fmaxf(0.0f, x0 * W[2] + x1 * W[5] + x2 * W[8] + bias[2]);
    ((float4*)sNext)[node] = make_float4(h0 * n, h1 * n, h2 * n, 0.0f);
  }
}

// Layer 5 (3->3) + layer-6 pre-transform: sB = (relu(agg*n @ W5 + b5) @ W6) * n
__global__ __launch_bounds__(BTL) void k_layer5(
    const int* __restrict__ scanT, const unsigned int* __restrict__ packed,
    const float* __restrict__ sPrev, const float* __restrict__ norm,
    const float* __restrict__ W5, const float* __restrict__ b5,
    const float* __restrict__ W6, float* __restrict__ sB, int N) {
  __shared__ float a0[BSIZE], a1[BSIZE], a2[BSIZE];
  int k = blockIdx.x;
  for (int i = threadIdx.x; i < BSIZE; i += BTL) { a0[i] = 0.0f; a1[i] = 0.0f; a2[i] = 0.0f; }
  int beg = scanT[k], end = scanT[k + 1];
  __syncthreads();
  int abeg = min(end, (beg + 7) & ~7);
  {
    int t = beg + (int)threadIdx.x;
    if (t < abeg) ACC3(packed[t]);
  }
  int i = abeg + (int)threadIdx.x * 8;
  for (; i + 7 < end; i += BTL * 8) {
    uint4 pa = *(const uint4*)(packed + i);
    uint4 pb = *(const uint4*)(packed + i + 4);
    float4 m0 = ((const float4*)sPrev)[pa.x >> BSHIFT];
    float4 m1 = ((const float4*)sPrev)[pa.y >> BSHIFT];
    float4 m2 = ((const float4*)sPrev)[pa.z >> BSHIFT];
    float4 m3 = ((const float4*)sPrev)[pa.w >> BSHIFT];
    float4 m4 = ((const float4*)sPrev)[pb.x >> BSHIFT];
    float4 m5 = ((const float4*)sPrev)[pb.y >> BSHIFT];
    float4 m6 = ((const float4*)sPrev)[pb.z >> BSHIFT];
    float4 m7 = ((const float4*)sPrev)[pb.w >> BSHIFT];
    atomicAdd(&a0[pa.x & LMASK], m0.x); atomicAdd(&a1[pa.x & LMASK], m0.y); atomicAdd(&a2[pa.x & LMASK], m0.z);
    atomicAdd(&a0[pa.y & LMASK], m1.x); atomicAdd(&a1[pa.y & LMASK], m1.y); atomicAdd(&a2[pa.y & LMASK], m1.z);
    atomicAdd(&a0[pa.z & LMASK], m2.x); atomicAdd(&a1[pa.z & LMASK], m2.y); atomicAdd(&a2[pa.z & LMASK], m2.z);
    atomicAdd(&a0[pa.w & LMASK], m3.x); atomicAdd(&a1[pa.w & LMASK], m3.y); atomicAdd(&a2[pa.w & LMASK], m3.z);
    atomicAdd(&a0[pb.x & LMASK], m4.x); atomicAdd(&a1[pb.x & LMASK], m4.y); atomicAdd(&a2[pb.x & LMASK], m4.z);
    atomicAdd(&a0[pb.y & LMASK], m5.x); atomicAdd(&a1[pb.y & LMASK], m5.y); atomicAdd(&a2[pb.y & LMASK], m5.z);
    atomicAdd(&a0[pb.z & LMASK], m6.x); atomicAdd(&a1[pb.z & LMASK], m6.y); atomicAdd(&a2[pb.z & LMASK], m6.z);
    atomicAdd(&a0[pb.w & LMASK], m7.x); atomicAdd(&a1[pb.w & LMASK], m7.y); atomicAdd(&a2[pb.w & LMASK], m7.z);
  }
  for (; i < end; ++i) ACC3(packed[i]);
  __syncthreads();
  int node0 = k << BSHIFT;
  for (int tt = threadIdx.x; tt < BSIZE; tt += BTL) {
    int node = node0 + tt;
    if (node >= N) break;
    float n = norm[node];
    float x0 = a0[tt] * n, x1 = a1[tt] * n, x2 = a2[tt] * n;
    float h0 = fmaxf(0.0f, x0 * W5[0] + x1 * W5[3] + x2 * W5[6] + b5[0]);
    float h1 = fmaxf(0.0f, x0 * W5[1] + x1 * W5[4] + x2 * W5[7] + b5[1]);
    float h2 = fmaxf(0.0f, x0 * W5[2] + x1 * W5[5] + x2 * W5[8] + b5[2]);
    sB[node] = (h0 * W6[0] + h1 * W6[1] + h2 * W6[2]) * n;
  }
}

// Layer 6 (scalar): out = relu(agg * n + b6)
__global__ __launch_bounds__(BTL) void k_layer6(
    const int* __restrict__ scanT, const unsigned int* __restrict__ packed,
    const float* __restrict__ sIn, const float* __restrict__ norm,
    const float* __restrict__ b6, float* __restrict__ out, int N) {
  __shared__ float a[BSIZE];
  int k = blockIdx.x;
  for (int i = threadIdx.x; i < BSIZE; i += BTL) a[i] = 0.0f;
  int beg = scanT[k], end = scanT[k + 1];
  __syncthreads();
  int abeg = min(end, (beg + 7) & ~7);
  {
    int t = beg + (int)threadIdx.x;
    if (t < abeg) ACC1(packed[t]);
  }
  int i = abeg + (int)threadIdx.x * 8;
  for (; i + 7 < end; i += BTL * 8) {
    uint4 pa = *(const uint4*)(packed + i);
    uint4 pb = *(const uint4*)(packed + i + 4);
    float m0 = sIn[pa.x >> BSHIFT];
    float m1 = sIn[pa.y >> BSHIFT];
    float m2 = sIn[pa.z >> BSHIFT];
    float m3 = sIn[pa.w >> BSHIFT];
    float m4 = sIn[pb.x >> BSHIFT];
    float m5 = sIn[pb.y >> BSHIFT];
    float m6 = sIn[pb.z >> BSHIFT];
    float m7 = sIn[pb.w >> BSHIFT];
    atomicAdd(&a[pa.x & LMASK], m0);
    atomicAdd(&a[pa.y & LMASK], m1);
    atomicAdd(&a[pa.z & LMASK], m2);
    atomicAdd(&a[pa.w & LMASK], m3);
    atomicAdd(&a[pb.x & LMASK], m4);
    atomicAdd(&a[pb.y & LMASK], m5);
    atomicAdd(&a[pb.z & LMASK], m6);
    atomicAdd(&a[pb.w & LMASK], m7);
  }
  for (; i < end; ++i) ACC1(packed[i]);
  __syncthreads();
  int node0 = k << BSHIFT;
  for (int tt = threadIdx.x; tt < BSIZE; tt += BTL) {
    int node = node0 + tt;
    if (node >= N) break;
    out[node] = fmaxf(0.0f, a[tt] * norm[node] + b6[0]);
  }
}

extern "C" void kernel_launch(void* const* d_in, const int* in_sizes, int n_in,
                              void* d_out, int out_size, void* d_ws, size_t ws_size,
                              hipStream_t stream) {
  const float* feat = (const float*)d_in[0];
  const float* norm = (const float*)d_in[1];
  const int* src = (const int*)d_in[2];
  const int* dst = (const int*)d_in[3];
  const float* W1 = (const float*)d_in[4];
  const float* b1 = (const float*)d_in[5];
  const float* W2 = (const float*)d_in[6];
  const float* b2 = (const float*)d_in[7];
  const float* W3 = (const float*)d_in[8];
  const float* b3 = (const float*)d_in[9];
  const float* W4 = (const float*)d_in[10];
  const float* b4 = (const float*)d_in[11];
  const float* W5 = (const float*)d_in[12];
  const float* b5 = (const float*)d_in[13];
  const float* W6 = (const float*)d_in[14];
  const float* b6 = (const float*)d_in[15];
  float* out = (float*)d_out;

  const int N = in_sizes[0];
  const int E = in_sizes[2];
  const int nbNode = (N + BT - 1) / BT;
  const int nBkt = (N + BSIZE - 1) >> BSHIFT;                 // 245
  const int chunk = (((E + NBLK - 1) / NBLK) + 3) & ~3;

  // Workspace: packed[E] | histB[M] | histT[M] | scanT[M] | partial[M/BT] |
  //            s0B[N]f | sA[4N]f | sA2[4N]f    (~101 MB)
  unsigned int* packed = (unsigned int*)d_ws;
  int* histB = (int*)(packed + (size_t)E);
  int* histT = histB + (size_t)M;
  int* scanT = histT + (size_t)M;
  int* partial = scanT + (size_t)M;
  float* s0B = (float*)(partial + M / BT);
  float* sA = s0B + (size_t)N;
  float* sA2 = sA + (size_t)4 * N;

  // --- Build: dst-bucket partition + per-bucket src sort ---
  k_init<<<nbNode, BT, 0, stream>>>(feat, norm, s0B, N);
  k_phist<<<NBLK, BT, 0, stream>>>(dst, histB, E, chunk);
  {
    dim3 g1(NBKT / 64, NBLK / 64);
    k_transp<<<g1, BT, 0, stream>>>(histB, histT, NBLK, NBKT);
  }
  k_blockSum<<<M / BT, BT, 0, stream>>>(histT, partial, M);
  k_scanPartials<<<1, BT, 0, stream>>>(partial, M / BT);
  k_scanFinal<<<M / BT, BT, 0, stream>>>(histT, partial, M);
  {
    dim3 g2(NBLK / 64, NBKT / 64);
    k_transp<<<g2, BT, 0, stream>>>(histT, scanT, NBKT, NBLK);
  }
  k_pscatter<<<NBLK, BT, 0, stream>>>(src, dst, scanT, packed, E, chunk);
  k_sortB<<<nBkt, BTL, 0, stream>>>(scanT, packed);  // src-ascending per bucket

  // --- 6 fused layers ---
  k_layer1<<<nBkt, BTL, 0, stream>>>(scanT, packed, s0B, norm, W1, b1, sA, N);
  k_layer3<<<nBkt, BTL, 0, stream>>>(scanT, packed, sA, norm, W2, b2, sA2, N);
  k_layer3<<<nBkt, BTL, 0, stream>>>(scanT, packed, sA2, norm, W3, b3, sA, N);
  k_layer3<<<nBkt, BTL, 0, stream>>>(scanT, packed, sA, norm, W4, b4, sA2, N);
  k_layer5<<<nBkt, BTL, 0, stream>>>(scanT, packed, sA2, norm, W5, b5, W6, s0B, N);
  k_layer6<<<nBkt, BTL, 0, stream>>>(scanT, packed, s0B, norm, b6, out, N);
}